// Round 14
// baseline (124.340 us; speedup 1.0000x reference)
//
#include <hip/hip_runtime.h>
#include <hip/hip_bf16.h>

// Mean-shift: 3 iterations of X <- eta * X @ (K/deg) + (1-eta) * X,
// K = exp(2 * X^T X), D=32, N=9216. Fused attention formulation.
// R15: R14 (122.7us) done on overhead side. msattn ledger: R12 halved
// chunk-execs AND LDS reads at constant work -> null; occupancy/barriers/
// drain all null -> time ~ serial per-wave pipe sum, dominated by LDS
// broadcast amplification (8 waves read the SAME tile frags: 16KB read
// per wave-chunk from 8KB staged) + barrier lockstep that sharing forces.
// R15 flips the parallelization axis: waves own KEYS, not queries. Each
// wave handles all 144 block-queries x its own 32-key slice per 256-key
// chunk. Then every operand frag (K-subtile, V-frag) is a per-lane
// contiguous 16B GLOBAL load (rows / sigma-permuted cols line up exactly:
// sigma is precisely the GEMM2 slot<->key map of a 32-key slice) ->
// NO LDS staging, NO barriers in the main loop; waves fully independent.
// Global traffic 85MB/iter (same as shared-LDS: both amortize 8x),
// L2-resident. Q in registers (9 x v8bf from new SCALE-folded rows_s --
// bit-identical to the old afrag). 45 MFMA : 4 loads per wave-chunk.
// Grid = 64 q-blocks x KSEG=4 = exactly 256 blocks = 1/CU, 9 uniform
// chunks/segment. Epilogue: 3-round 8-wave LDS tree reduce (54KB).
// Kept: sigma-permuted cols, den on MFMA pipe, R14 parallel-burst reduce
// (now KSEG=4), coalesced pack.

#define DIM 32
#define RESO 96
#define NPT (RESO * RESO)          // 9216
#define NITER 3
#define ETA 0.5f
#define SCALE 2.88539008f          // BW * log2(e) = 2 * 1.4426950408

#define QB 144                     // queries per block (9 groups of 16)
#define NQB (NPT / QB)             // 64
#define NG 9                       // q-groups per wave
#define KSEG 4                     // key segments (grid.y) -> 256 blocks
#define CHUNK 256                  // keys per chunk (8 waves x 32)
#define NCHUNK (NPT / CHUNK)       // 36 chunks (9 per segment)

typedef __bf16 bf16_t;
typedef __bf16 v8bf __attribute__((ext_vector_type(8)));
typedef float  v4f  __attribute__((ext_vector_type(4)));

// Inverse of the 32-key slot permutation sigma(p) = 16*((p>>2)&1) +
// 4*(p>>3) + (p&3) (slot p in a GEMM2 A/B-frag <-> key offset sigma(p) in
// its 32-key block). cols is stored key-permuted so the V B-frag read is a
// contiguous 16B/lane. keyinv(sigma(p)) == p; bijection on [0,32).
__device__ __forceinline__ int keyinv(int m) {
    return ((m & 8) << 1) | ((m & 4) << 1) | ((m & 16) >> 2) | (m & 3);
}

// One-time pack of fp32 X (DIM x NPT) into bf16 row-major rows (NPT x DIM),
// SCALE-folded rows_s, and key-permuted col-major cols; also copies X into
// d_out slice 0. 32x32 LDS transpose tile; all global accesses coalesced.
// Grid = NPT/32 = 288 blocks x 256 threads.
__global__ __launch_bounds__(256, 4)
void pack_kernel(const float* __restrict__ X,
                 bf16_t* __restrict__ rows,
                 bf16_t* __restrict__ rows_s,
                 bf16_t* __restrict__ cols,
                 float* __restrict__ out_copy) {
    __shared__ float tt[32][33];
    const int tid = threadIdx.x;
    const int n0  = blockIdx.x * 32;
    const int inv = keyinv(tid & 31);

    // read 32d x 32n (d-major, n contiguous); cols scatter stays in one
    // 64B window per 32-key block.
#pragma unroll
    for (int j = 0; j < 4; ++j) {
        int d = (tid >> 5) + j * 8;
        int n = tid & 31;
        float v = X[(size_t)d * NPT + n0 + n];
        tt[d][n] = v;
        cols[(size_t)d * NPT + n0 + inv] = (bf16_t)v;
        out_copy[(size_t)d * NPT + n0 + n] = v;
    }
    __syncthreads();

    // write rows / rows_s (n-major, d contiguous): coalesced
#pragma unroll
    for (int j = 0; j < 4; ++j) {
        int n = (tid >> 5) + j * 8;
        int d = tid & 31;
        float v = tt[d][n];
        rows[(size_t)(n0 + n) * DIM + d]   = (bf16_t)v;
        rows_s[(size_t)(n0 + n) * DIM + d] = (bf16_t)(v * SCALE);
    }
}

// Fused mean-shift partial kernel, key-split waves. Block = 512 thr = 8
// waves; block covers 144 queries (qb) x key segment ks (9 chunks of 256
// keys). Wave w owns keys [kc + w*32, +32) of each chunk: all operand
// frags are direct per-lane-contiguous global loads (L2-resident), no LDS,
// no barriers until the epilogue 8-wave reduce. P in-register via swapped
// GEMM1; den rides the MFMA pipe.
__global__ __launch_bounds__(512, 2)
void msattn_kernel(const bf16_t* __restrict__ rows,
                   const bf16_t* __restrict__ rows_s,
                   const bf16_t* __restrict__ cols,
                   float* __restrict__ part_num,
                   float* __restrict__ part_den) {
    __shared__ float osum[8][48][33];   // 50.7KB: 3-round tree reduce buffer
    __shared__ float dsum[8][QB];       // 4.6KB

    const int tid  = threadIdx.x;
    const int w    = tid >> 6;
    const int lane = tid & 63;
    const int quad = lane >> 4;
    const int l16  = lane & 15;
    const int qb   = blockIdx.x;
    const int ks   = blockIdx.y;
    const int c0   = ks * (NCHUNK / KSEG);          // 9 chunks per segment
    const int c1   = c0 + (NCHUNK / KSEG);
    const int q0   = qb * QB;

    // Q-frags (GEMM1 B operand), SCALE pre-folded in rows_s:
    // qf[g][j] = X[dim quad*8+j][q0+g*16+l16] * SCALE  (bit-identical to old)
    v8bf qf[NG];
#pragma unroll
    for (int g = 0; g < NG; ++g)
        qf[g] = *(const v8bf*)&rows_s[(size_t)(q0 + g * 16 + l16) * DIM + quad * 8];

    v8bf ones;
#pragma unroll
    for (int j = 0; j < 8; ++j) ones[j] = (bf16_t)1.0f;

    // Frag sources (advance 256 keys per chunk):
    // ka: rows[kb + sub*16 + l16][dims quad*8..+7], kb = c*256 + w*32
    // bV: cols_perm[dim h*16+l16][kb + quad*8..+7]  (slot p <-> key sigma(p))
    const bf16_t* pA = rows + ((size_t)(c0 * CHUNK + w * 32 + l16)) * DIM + quad * 8;
    const bf16_t* pB = cols + (size_t)l16 * NPT + c0 * CHUNK + w * 32 + quad * 8;

    v4f acc[NG][2];                      // O[q=g*16+quad*4+r][d=h*16+l16]
    v4f den[NG];                         // row-sums (all 16 cols equal)
#pragma unroll
    for (int g = 0; g < NG; ++g) {
        acc[g][0] = (v4f){0.f, 0.f, 0.f, 0.f};
        acc[g][1] = (v4f){0.f, 0.f, 0.f, 0.f};
        den[g]    = (v4f){0.f, 0.f, 0.f, 0.f};
    }

    // Prologue: load chunk c0's four frags.
    v8bf ka0 = *(const v8bf*)pA;
    v8bf ka1 = *(const v8bf*)(pA + 16 * DIM);
    v8bf bV0 = *(const v8bf*)pB;
    v8bf bV1 = *(const v8bf*)(pB + (size_t)16 * NPT);
    pA += CHUNK * DIM;
    pB += CHUNK;

    for (int c = c0; c < c1; ++c) {
        const bool more = (c + 1 < c1);
        v8bf nka0, nka1, nb0, nb1;
        if (more) {                      // prefetch next chunk into registers
            nka0 = *(const v8bf*)pA;
            nka1 = *(const v8bf*)(pA + 16 * DIM);
            nb0  = *(const v8bf*)pB;
            nb1  = *(const v8bf*)(pB + (size_t)16 * NPT);
            pA += CHUNK * DIM;
            pB += CHUNK;
        }

#pragma unroll
        for (int g = 0; g < NG; ++g) {
            // GEMM1 (swapped): D[m=key sub*16+quad*4+r][n=query g*16+l16]
            v4f s0 = __builtin_amdgcn_mfma_f32_16x16x32_bf16(ka0, qf[g],
                         (v4f){0.f, 0.f, 0.f, 0.f}, 0, 0, 0);
            v4f s1 = __builtin_amdgcn_mfma_f32_16x16x32_bf16(ka1, qf[g],
                         (v4f){0.f, 0.f, 0.f, 0.f}, 0, 0, 0);
            // exp2 + pack: slot p=quad*8+j <-> key sigma(p) = 16*(j>>2) +
            // 4*quad + (j&3): j 0..3 from s0 (keys 0..15), j 4..7 from s1.
            v8bf pa;
#pragma unroll
            for (int r = 0; r < 4; ++r) {
                pa[r]     = (bf16_t)__builtin_amdgcn_exp2f(s0[r]);
                pa[4 + r] = (bf16_t)__builtin_amdgcn_exp2f(s1[r]);
            }
            // GEMM2: O[q][d] += P V; den on the MFMA pipe.
            acc[g][0] = __builtin_amdgcn_mfma_f32_16x16x32_bf16(pa, bV0, acc[g][0], 0, 0, 0);
            acc[g][1] = __builtin_amdgcn_mfma_f32_16x16x32_bf16(pa, bV1, acc[g][1], 0, 0, 0);
            den[g]    = __builtin_amdgcn_mfma_f32_16x16x32_bf16(pa, ones, den[g], 0, 0, 0);
        }

        if (more) { ka0 = nka0; ka1 = nka1; bV0 = nb0; bV1 = nb1; }
    }

    // --- epilogue: 8-wave reduce over key-slices. den first (read after
    // the round-0 barrier), then 3 rounds of 3 q-groups through osum. ---
    if (l16 == 0) {
#pragma unroll
        for (int g = 0; g < NG; ++g)
#pragma unroll
            for (int r = 0; r < 4; ++r)
                dsum[w][g * 16 + quad * 4 + r] = den[g][r];
    }

#pragma unroll
    for (int round = 0; round < 3; ++round) {
        if (round) __syncthreads();      // protect osum reuse
#pragma unroll
        for (int gg = 0; gg < 3; ++gg) {
            int g = round * 3 + gg;
#pragma unroll
            for (int h = 0; h < 2; ++h)
#pragma unroll
                for (int r = 0; r < 4; ++r)
                    osum[w][gg * 16 + quad * 4 + r][h * 16 + l16] = acc[g][h][r];
        }
        __syncthreads();
        // combine 48q x 32d outputs: 512 thr x 3 each; coalesced stores.
#pragma unroll
        for (int e = 0; e < 3; ++e) {
            int idx = tid + e * 512;
            int qr = idx >> 5, d = idx & 31;
            float s = osum[0][qr][d] + osum[1][qr][d] + osum[2][qr][d]
                    + osum[3][qr][d] + osum[4][qr][d] + osum[5][qr][d]
                    + osum[6][qr][d] + osum[7][qr][d];
            part_num[((size_t)ks * NPT + q0 + round * 48 + qr) * DIM + d] = s;
        }
    }
    if (tid < QB) {
        float s = dsum[0][tid] + dsum[1][tid] + dsum[2][tid] + dsum[3][tid]
                + dsum[4][tid] + dsum[5][tid] + dsum[6][tid] + dsum[7][tid];
        part_den[ks * NPT + q0 + tid] = s;
    }
}

// Reduce KSEG=4 partials, apply eta-step, write Xnext + next iteration's
// rows/rows_s/cols. One parallel global-read burst (R14), then LDS combine
// + coalesced writes. Grid = NPT/32 = 288 blocks x 512 threads.
__global__ __launch_bounds__(512, 2)
void reduce_kernel(const float* __restrict__ part_num,
                   const float* __restrict__ part_den,
                   const float* __restrict__ Xcur,
                   float* __restrict__ Xnext,
                   bf16_t* __restrict__ rows_out,
                   bf16_t* __restrict__ rows_s_out,
                   bf16_t* __restrict__ cols_out) {
    __shared__ float tp[2][32][33];   // per-half num sums
    __shared__ float dpart[KSEG][32];
    __shared__ float txn[32][33];

    const int tid = threadIdx.x;
    const int q0  = blockIdx.x * 32;
    const int inv = keyinv(tid & 31);

    // Phase A: one parallel global-read burst.
    {
        int slot = tid & 255;          // (qq, dq)
        int sh   = tid >> 8;           // half: ss {0,1} / {2,3}
        int qq = slot >> 3, dq = slot & 7;
        const float* pb = &part_num[(size_t)(q0 + qq) * DIM + dq * 4];
        size_t seg = (size_t)NPT * DIM;
        v4f s = *(const v4f*)&pb[(2 * sh) * seg]
              + *(const v4f*)&pb[(2 * sh + 1) * seg];
#pragma unroll
        for (int k = 0; k < 4; ++k) tp[sh][qq][dq * 4 + k] = s[k];
    }
    if (tid < KSEG * 32) {
        int ss = tid >> 5, q = tid & 31;
        dpart[ss][q] = part_den[ss * NPT + q0 + q];
    }
    __syncthreads();

    // Phase B (d-major: Xcur read, Xnext + cols writes coalesced).
#pragma unroll
    for (int e = 0; e < 2; ++e) {
        int idx = tid + e * 512;
        int d = idx >> 5, qq = idx & 31;
        float num = tp[0][qq][d] + tp[1][qq][d];
        float dn = dpart[0][qq] + dpart[1][qq] + dpart[2][qq] + dpart[3][qq];
        float xo = Xcur[(size_t)d * NPT + q0 + qq];
        float xn = ETA * num / dn + (1.0f - ETA) * xo;
        Xnext[(size_t)d * NPT + q0 + qq] = xn;
        cols_out[(size_t)d * NPT + q0 + inv] = (bf16_t)xn;
        txn[qq][d] = xn;
    }
    __syncthreads();

    // Phase C (q-major: rows/rows_s coalesced).
#pragma unroll
    for (int e = 0; e < 2; ++e) {
        int idx = tid + e * 512;
        int qq = idx >> 5, d = idx & 31;
        float v = txn[qq][d];
        rows_out[(size_t)(q0 + qq) * DIM + d]   = (bf16_t)v;
        rows_s_out[(size_t)(q0 + qq) * DIM + d] = (bf16_t)(v * SCALE);
    }
}

extern "C" void kernel_launch(void* const* d_in, const int* in_sizes, int n_in,
                              void* d_out, int out_size, void* d_ws, size_t ws_size,
                              hipStream_t stream) {
    const float* x_in = (const float*)d_in[0];
    float* out = (float*)d_out;

    const size_t DN = (size_t)DIM * NPT;
    // Workspace: 6 bf16 pack buffers (ping-pong rows/rows_s/cols), partials.
    bf16_t* rows0  = (bf16_t*)d_ws;
    bf16_t* rowss0 = rows0 + DN;
    bf16_t* cols0  = rowss0 + DN;
    bf16_t* rows1  = cols0 + DN;
    bf16_t* rowss1 = rows1 + DN;
    bf16_t* cols1  = rowss1 + DN;
    float* part_num = (float*)(cols1 + DN);                 // KSEG * NPT * DIM f32
    float* part_den = part_num + (size_t)KSEG * NPT * DIM;  // KSEG * NPT f32

    pack_kernel<<<NPT / 32, 256, 0, stream>>>(x_in, rows0, rowss0, cols0, out);

    for (int it = 0; it < NITER; ++it) {
        const float* Xcur = (it == 0) ? x_in : out + (size_t)it * DN;
        bf16_t* rin   = (it & 1) ? rows1 : rows0;
        bf16_t* rsin  = (it & 1) ? rowss1 : rowss0;
        bf16_t* cin   = (it & 1) ? cols1 : cols0;
        bf16_t* rout  = (it & 1) ? rows0 : rows1;
        bf16_t* rsout = (it & 1) ? rowss0 : rowss1;
        bf16_t* cout  = (it & 1) ? cols0 : cols1;
        msattn_kernel<<<dim3(NQB, KSEG), 512, 0, stream>>>(rin, rsin, cin,
                                                           part_num, part_den);
        reduce_kernel<<<NPT / 32, 512, 0, stream>>>(part_num, part_den, Xcur,
                                                    out + (size_t)(it + 1) * DN,
                                                    rout, rsout, cout);
    }
}